// Round 8
// baseline (309.980 us; speedup 1.0000x reference)
//
#include <hip/hip_runtime.h>

#define B_   8
#define N_   1024
#define D_   512
#define H_   8
#define DH_  64
#define SCALE_ 0.044194173824159216f   // 1/sqrt(512)
#define LOG2E_ 1.4426950408889634f

typedef __attribute__((ext_vector_type(8))) short bf16x8;
typedef __attribute__((ext_vector_type(4))) float f32x4;
typedef __attribute__((ext_vector_type(8))) unsigned short us8;
typedef __attribute__((ext_vector_type(4))) unsigned int u32x4;

__device__ __forceinline__ unsigned short f2bf(float f) {
  unsigned u = __builtin_bit_cast(unsigned, f);
  u += 0x7fffu + ((u >> 16) & 1u);           // RNE
  return (unsigned short)(u >> 16);
}
__device__ __forceinline__ float bf2f(unsigned short h) {
  unsigned u = ((unsigned)h) << 16;
  return __builtin_bit_cast(float, u);
}
__device__ __forceinline__ void gl_lds16(const void* g, void* l) {
  __builtin_amdgcn_global_load_lds(
      (const __attribute__((address_space(1))) unsigned int*)g,
      (__attribute__((address_space(3))) unsigned int*)l, 16, 0, 0);
}
__device__ __forceinline__ unsigned cvt_pk_bf16(float lo, float hi) {
  unsigned r;
  asm("v_cvt_pk_bf16_f32 %0, %1, %2" : "=v"(r) : "v"(lo), "v"(hi));
  return r;
}
#define MFMA16(a, b, c) __builtin_amdgcn_mfma_f32_16x16x32_bf16((a), (b), (c), 0, 0, 0)

// ---------------------------------------------------------------------------
// prep: WT_swz[mat][n][kmap] = bf16(W[k][n]); kmap XOR-swizzled so that a
// LINEAR global_load_lds copy + XOR on the ds_read side is bank-conflict-free.
// ---------------------------------------------------------------------------
__global__ void prep_w(const float* __restrict__ Wq, const float* __restrict__ Wk,
                       const float* __restrict__ Wv, const float* __restrict__ Wo,
                       unsigned short* __restrict__ WT) {
  int idx = blockIdx.x * 256 + threadIdx.x;          // 4 * 512 * 512 total
  int mat = idx >> 18;
  int rem = idx & 0x3FFFF;
  int k = rem >> 9, n = rem & 511;
  const float* W = (mat == 0) ? Wq : (mat == 1) ? Wk : (mat == 2) ? Wv : Wo;
  float v = W[(size_t)k * 512 + n];
  int kmap = (k & ~63) | ((k & 63) ^ ((n & 7) << 3));
  WT[(size_t)mat * 262144 + (size_t)n * 512 + kmap] = f2bf(v);
}

// mbits[j] bit b = (mask[b][j] != 0)
__global__ void prep_mask(const float* __restrict__ mask, unsigned* __restrict__ mbits) {
  int j = blockIdx.x * 256 + threadIdx.x;            // 1024 total
  unsigned r = 0;
#pragma unroll
  for (int bb = 0; bb < 8; ++bb) r |= (mask[bb * N_ + j] != 0.f ? 1u : 0u) << bb;
  mbits[j] = r;
}

// ---------------------------------------------------------------------------
// GEMM core body (128x128 tile, BK=64, 4 waves 2x2, wave = 64x64 out)
// ---------------------------------------------------------------------------
#define GEMM_BODY(A, W, bias, EPILOGUE)                                          \
  __shared__ unsigned short Alds[2][128][72];                                    \
  __shared__ unsigned short Blds[2][128 * 64];                                   \
  const int t = threadIdx.x, w = t >> 6, l = t & 63;                             \
  const int wr = w >> 1, wc = w & 1;                                             \
  const int lm = l & 15, lg = l >> 4;                                            \
  const int bm = blockIdx.x >> 2, bn = blockIdx.x & 3;                           \
  f32x4 acc[4][4];                                                               \
  _Pragma("unroll") for (int mt = 0; mt < 4; ++mt)                               \
  _Pragma("unroll") for (int nt = 0; nt < 4; ++nt)                               \
      acc[mt][nt] = f32x4{0.f, 0.f, 0.f, 0.f};                                   \
  float4 areg[8];                                                                \
  auto loadA = [&](int kt) {                                                     \
    _Pragma("unroll") for (int p = 0; p < 8; ++p) {                              \
      int row = (t >> 4) + p * 16, col = (t & 15) * 4;                           \
      areg[p] = *(const float4*)&A[((size_t)(bm * 128 + row)) * 512 + kt * 64 + col]; \
    }                                                                            \
  };                                                                             \
  auto issueB = [&](int kt, int sb) {                                            \
    _Pragma("unroll") for (int p = 0; p < 4; ++p) {                              \
      int chunk = w * 4 + p;                                                     \
      int row = chunk * 8 + (l >> 3), gc = kt * 64 + (l & 7) * 8;                \
      gl_lds16(&W[((size_t)(bn * 128 + row)) * 512 + gc],                        \
               &Blds[sb][chunk * 512 + l * 8]);                                  \
    }                                                                            \
  };                                                                             \
  auto writeA = [&](int sb) {                                                    \
    _Pragma("unroll") for (int p = 0; p < 8; ++p) {                              \
      int row = (t >> 4) + p * 16, col = (t & 15) * 4;                           \
      float4 v = areg[p];                                                        \
      uint2 d;                                                                   \
      d.x = (unsigned)f2bf(v.x) | ((unsigned)f2bf(v.y) << 16);                   \
      d.y = (unsigned)f2bf(v.z) | ((unsigned)f2bf(v.w) << 16);                   \
      *(uint2*)&Alds[sb][row][col] = d;                                          \
    }                                                                            \
  };                                                                             \
  loadA(0); issueB(0, 0); writeA(0);                                             \
  __syncthreads();                                                               \
  int buf = 0;                                                                   \
  for (int kt = 0; kt < 8; ++kt) {                                               \
    if (kt + 1 < 8) { loadA(kt + 1); issueB(kt + 1, buf ^ 1); }                  \
    _Pragma("unroll") for (int kk = 0; kk < 2; ++kk) {                           \
      bf16x8 af[4], bfv[4];                                                      \
      _Pragma("unroll") for (int mt = 0; mt < 4; ++mt)                           \
        af[mt] = *(const bf16x8*)&Alds[buf][wr * 64 + mt * 16 + lm][kk * 32 + lg * 8]; \
      _Pragma("unroll") for (int nt = 0; nt < 4; ++nt) {                         \
        int rr = wc * 64 + nt * 16 + lm;                                         \
        int c = (kk * 32 + lg * 8) ^ ((rr & 7) << 3);                            \
        bfv[nt] = *(const bf16x8*)&Blds[buf][rr * 64 + c];                       \
      }                                                                          \
      _Pragma("unroll") for (int mt = 0; mt < 4; ++mt)                           \
      _Pragma("unroll") for (int nt = 0; nt < 4; ++nt)                           \
          acc[mt][nt] = MFMA16(af[mt], bfv[nt], acc[mt][nt]);                    \
    }                                                                            \
    if (kt + 1 < 8) writeA(buf ^ 1);                                             \
    __syncthreads();                                                             \
    buf ^= 1;                                                                    \
  }                                                                              \
  _Pragma("unroll") for (int mt = 0; mt < 4; ++mt)                               \
  _Pragma("unroll") for (int nt = 0; nt < 4; ++nt) {                             \
    int gn = bn * 128 + wc * 64 + nt * 16 + lm;                                  \
    float bv_ = bias[gn];                                                        \
    _Pragma("unroll") for (int e = 0; e < 4; ++e) {                              \
      int gm = bm * 128 + wr * 64 + mt * 16 + lg * 4 + e;                        \
      float v = acc[mt][nt][e] + bv_;                                            \
      size_t off = (size_t)gm * 512 + gn;                                        \
      EPILOGUE                                                                   \
    }                                                                            \
  }

// fused 3 projection GEMMs: blockIdx.y = {0:Q->qb, 1:K->kb, 2:K->vtmp}
__global__ __launch_bounds__(256, 2) void gemm_proj3(
    const float* __restrict__ Q, const float* __restrict__ K,
    const unsigned short* __restrict__ WT,
    const float* __restrict__ bq, const float* __restrict__ bk,
    const float* __restrict__ bv, const float* __restrict__ mask,
    unsigned short* __restrict__ qb, unsigned short* __restrict__ kb,
    unsigned short* __restrict__ vtmp) {
  const int mat = blockIdx.y;
  const float* A = (mat == 0) ? Q : K;
  const unsigned short* W = WT + (size_t)mat * 262144;
  const float* bias = (mat == 0) ? bq : (mat == 1) ? bk : bv;
  unsigned short* outp = (mat == 0) ? qb : (mat == 1) ? kb : vtmp;
  GEMM_BODY(A, W, bias, { outp[off] = f2bf(v * mask[gm]); })
}

// final GEMM: out_f32 = resid + relu(acc + bias) * mask
__global__ __launch_bounds__(256, 2) void gemm_final(
    const float* __restrict__ A, const unsigned short* __restrict__ W,
    const float* __restrict__ bias, const float* __restrict__ mask,
    const float* __restrict__ resid, float* __restrict__ outp) {
  GEMM_BODY(A, W, bias, { outp[off] = resid[off] + fmaxf(v, 0.f) * mask[gm]; })
}

// ---------------------------------------------------------------------------
// v transpose: vtmp[b][n][d] (bf16) -> vT[b][d][n] (bf16)
// ---------------------------------------------------------------------------
__global__ void vtrans_kernel(const unsigned short* __restrict__ vtmp,
                              unsigned short* __restrict__ vT) {
  __shared__ unsigned short T[64][72];
  int b = blockIdx.x, ntile = blockIdx.y, dtile = blockIdx.z;
  int n0 = ntile * 64, d0 = dtile * 64;
  int t = threadIdx.x;
#pragma unroll
  for (int p = 0; p < 2; ++p) {
    int r = (t >> 3) + p * 32;
    int c = (t & 7) * 8;
    *(us8*)&T[r][c] = *(const us8*)&vtmp[((size_t)(b * N_ + n0 + r)) * D_ + d0 + c];
  }
  __syncthreads();
#pragma unroll
  for (int p = 0; p < 2; ++p) {
    int r = (t >> 3) + p * 32;   // d-local
    int c = (t & 7) * 8;         // n-local
    us8 v;
#pragma unroll
    for (int e = 0; e < 8; ++e) v[e] = T[c + e][r];
    *(us8*)&vT[((size_t)(b * D_ + d0 + r)) * N_ + n0 + c] = v;
  }
}

// ---------------------------------------------------------------------------
// attn_score: block = (h, 64i x 32j tile). 8 waves = 8 batches.
// Phase 1 (wave=b): S = q k^T (K=64, 16 MFMA) -> Slds[b][i][j(+pad36)].
// ONE barrier. Phase 2 (thread=(i,4j)): read S (f32x4), U direct from global
// (native [i][j][b] layout -> 128B/thread fully coalesced), exp, write P bf16.
// No per-iteration phases -> no convoyed HBM-tail stalls (r2..r7 lesson).
// ---------------------------------------------------------------------------
__global__ __launch_bounds__(512, 4) void attn_score(
    const unsigned short* __restrict__ qb, const unsigned short* __restrict__ kb,
    const float* __restrict__ U, const unsigned* __restrict__ mbits,
    unsigned short* __restrict__ P, int h0, int lnh) {
  __shared__ float Slds[8 * 2304];   // [b][i64][36] = 72 KB -> 2 blocks/CU
  const int t = threadIdx.x, w = t >> 6, l = t & 63;
  const int bid = (int)blockIdx.x;
  const int h = h0 + (bid & ((1 << lnh) - 1));
  const int r = bid >> lnh;
  const int i0 = (r & 15) * 64, j0 = (r >> 4) * 32;
  const int lm = l & 15, lg = l >> 4;

  // ---- phase 1: per-wave QK^T for batch b = w
  bf16x8 qf[4][2], kf[2][2];
  {
    const unsigned short* qbase = qb + ((size_t)w * N_ + i0 + lm) * D_ + h * DH_ + lg * 8;
    const unsigned short* kbase = kb + ((size_t)w * N_ + j0 + lm) * D_ + h * DH_ + lg * 8;
#pragma unroll
    for (int mt = 0; mt < 4; ++mt)
#pragma unroll
      for (int kt = 0; kt < 2; ++kt)
        qf[mt][kt] = *(const bf16x8*)(qbase + (size_t)(mt * 16) * D_ + kt * 32);
#pragma unroll
    for (int nt = 0; nt < 2; ++nt)
#pragma unroll
      for (int kt = 0; kt < 2; ++kt)
        kf[nt][kt] = *(const bf16x8*)(kbase + (size_t)(nt * 16) * D_ + kt * 32);
  }
  f32x4 acc[4][2];
#pragma unroll
  for (int mt = 0; mt < 4; ++mt)
#pragma unroll
    for (int nt = 0; nt < 2; ++nt) acc[mt][nt] = f32x4{0.f, 0.f, 0.f, 0.f};
#pragma unroll
  for (int kt = 0; kt < 2; ++kt)
#pragma unroll
    for (int mt = 0; mt < 4; ++mt)
#pragma unroll
      for (int nt = 0; nt < 2; ++nt)
        acc[mt][nt] = MFMA16(qf[mt][kt], kf[nt][kt], acc[mt][nt]);
  // S -> LDS (D-layout: row = mt*16+lg*4+e, col = nt*16+lm); ~2-way conflicts
#pragma unroll
  for (int mt = 0; mt < 4; ++mt)
#pragma unroll
    for (int nt = 0; nt < 2; ++nt)
#pragma unroll
      for (int e = 0; e < 4; ++e)
        Slds[w * 2304 + (mt * 16 + lg * 4 + e) * 36 + nt * 16 + lm] = acc[mt][nt][e];

  // ---- U load for phase 2 (issued before the barrier; coalesced 128B/thread)
  const int ti = t >> 3, tj = (t & 7) * 4;   // thread owns (i=ti, j=tj..tj+3)
  const float* Ug = U + (((size_t)h * N_ + i0 + ti) * N_ + j0 + tj) * B_;
  float uu[32];
#pragma unroll
  for (int jj = 0; jj < 4; ++jj) {
    float4 a = *(const float4*)(Ug + jj * 8);
    float4 c = *(const float4*)(Ug + jj * 8 + 4);
    uu[jj * 8 + 0] = a.x; uu[jj * 8 + 1] = a.y; uu[jj * 8 + 2] = a.z; uu[jj * 8 + 3] = a.w;
    uu[jj * 8 + 4] = c.x; uu[jj * 8 + 5] = c.y; uu[jj * 8 + 6] = c.z; uu[jj * 8 + 7] = c.w;
  }
  const uint4 mb4 = *(const uint4*)&mbits[j0 + tj];
  const unsigned mbv[4] = {mb4.x, mb4.y, mb4.z, mb4.w};
  __syncthreads();

  // ---- phase 2: s = S*scale + U; p = mask_j ? exp(s) : 0; write P bf16
  unsigned short* Pb = P + ((size_t)(h - h0) * B_ * N_ + (size_t)(i0 + ti)) * N_ + j0 + tj;
#pragma unroll
  for (int b2 = 0; b2 < 8; ++b2) {
    f32x4 s4 = *(const f32x4*)&Slds[b2 * 2304 + ti * 36 + tj];
    float p[4];
#pragma unroll
    for (int jj = 0; jj < 4; ++jj) {
      float s = s4[jj] * SCALE_ + uu[jj * 8 + b2];
      p[jj] = ((mbv[jj] >> b2) & 1) ? exp2f(s * LOG2E_) : 0.f;
    }
    uint2 pw;
    pw.x = cvt_pk_bf16(p[0], p[1]);
    pw.y = cvt_pk_bf16(p[2], p[3]);
    *(uint2*)(Pb + (size_t)b2 * N_ * N_) = pw;
  }
}

// ---------------------------------------------------------------------------
// attn_pv: O = mask_i * (q + P@V / rowsum(P)).  No LDS, no barriers.
// Block = (h, b, 128-row i-tile), 8 waves x 16 rows. Denominator comes free
// from the A-fragments (sum elements over ksteps, reduce over lg).
// P prefetched 4 ksteps ahead (full unroll -> static indices, rule #20).
// ---------------------------------------------------------------------------
__global__ __launch_bounds__(512, 4) void attn_pv(
    const unsigned short* __restrict__ P, const unsigned short* __restrict__ vT,
    const unsigned short* __restrict__ qb, const float* __restrict__ mask,
    float* __restrict__ O32, int h0, int lnh) {
  const int t = threadIdx.x, w = t >> 6, l = t & 63;
  const int bid = (int)blockIdx.x;
  const int h = h0 + (bid & ((1 << lnh) - 1));
  const int r = bid >> lnh;
  const int b = r & 7, it = r >> 3;
  const int lm = l & 15, lg = l >> 4;
  const int i0 = it * 128 + w * 16;

  const unsigned short* Pb = P + (((size_t)(h - h0) * B_ + b) * N_ + i0 + lm) * N_ + lg * 8;
  const unsigned short* Vb = vT + ((size_t)b * D_ + h * DH_ + lm) * N_ + lg * 8;

  f32x4 acc[4];
#pragma unroll
  for (int nt = 0; nt < 4; ++nt) acc[nt] = f32x4{0.f, 0.f, 0.f, 0.f};
  float dsum = 0.f;

  bf16x8 pf[36];
#pragma unroll
  for (int ks = 0; ks < 4; ++ks) pf[ks] = *(const bf16x8*)(Pb + ks * 32);
#pragma unroll
  for (int ks = 0; ks < 32; ++ks) {
    if (ks + 4 < 32) pf[ks + 4] = *(const bf16x8*)(Pb + (ks + 4) * 32);
#pragma unroll
    for (int nt = 0; nt < 4; ++nt) {
      bf16x8 vf = *(const bf16x8*)(Vb + (size_t)(nt * 16) * N_ + ks * 32);
      acc[nt] = MFMA16(pf[ks], vf, acc[nt]);
    }
    u32x4 pw = __builtin_bit_cast(u32x4, pf[ks]);
#pragma unroll
    for (int q = 0; q < 4; ++q) {
      dsum += __builtin_bit_cast(float, pw[q] << 16);
      dsum += __builtin_bit_cast(float, pw[q] & 0xFFFF0000u);
    }
  }
  // reduce over lg (k-slices) -> every lane has full rowsum for row lm
  dsum += __shfl_xor(dsum, 16);
  dsum += __shfl_xor(dsum, 32);

#pragma unroll
  for (int e = 0; e < 4; ++e) {
    int gi = i0 + lg * 4 + e;
    float rs = __shfl(dsum, lg * 4 + e);   // rowsum of acc-row (lanes 0..15 hold rows 0..15)
    float mi = mask[b * N_ + gi];
    float rD = 1.f / (rs + 1e-16f);
#pragma unroll
    for (int nt = 0; nt < 4; ++nt) {
      size_t off = ((size_t)b * N_ + gi) * D_ + h * DH_ + lm + nt * 16;
      O32[off] = mi * (bf2f(qb[off]) + acc[nt][e] * rD);
    }
  }
}

// ---------------------------------------------------------------------------
extern "C" void kernel_launch(void* const* d_in, const int* in_sizes, int n_in,
                              void* d_out, int out_size, void* d_ws, size_t ws_size,
                              hipStream_t stream) {
  const float* Q    = (const float*)d_in[0];
  const float* K    = (const float*)d_in[1];
  const float* U    = (const float*)d_in[2];
  const float* mask = (const float*)d_in[3];
  const float* Wq   = (const float*)d_in[4];
  const float* bq   = (const float*)d_in[5];
  const float* Wk   = (const float*)d_in[6];
  const float* bk   = (const float*)d_in[7];
  const float* Wv   = (const float*)d_in[8];
  const float* bv   = (const float*)d_in[9];
  const float* Wo   = (const float*)d_in[10];
  const float* bo   = (const float*)d_in[11];
  float* out = (float*)d_out;

  char* ws = (char*)d_ws;
  const size_t MB = 1ull << 20;
  unsigned short* WT   = (unsigned short*)(ws);            // [0, 2) MB
  unsigned short* qbuf = (unsigned short*)(ws + 2 * MB);   // [2, 10)
  unsigned short* kbuf = (unsigned short*)(ws + 10 * MB);  // [10, 18)
  unsigned short* vTb  = (unsigned short*)(ws + 18 * MB);  // [18, 26)
  float*          O32  = (float*)(ws + 26 * MB);           // [26, 42)
  unsigned*       mbits= (unsigned*)(ws + 42 * MB);        // [42, 42.004)
  unsigned short* vtmp = (unsigned short*)(ws + 43 * MB);  // [43, 51) overlay in P region
  unsigned short* P    = (unsigned short*)(ws + 43 * MB);  // [43, 43 + nh*16)

  // choose h-group size from available workspace (P = nh * 16 MB)
  int lnh;
  if      (ws_size >= (43 + 128) * MB) lnh = 3;
  else if (ws_size >= (43 + 64) * MB)  lnh = 2;
  else if (ws_size >= (43 + 32) * MB)  lnh = 1;
  else                                 lnh = 0;
  const int nh = 1 << lnh;

  prep_w<<<4096, 256, 0, stream>>>(Wq, Wk, Wv, Wo, WT);
  prep_mask<<<4, 256, 0, stream>>>(mask, mbits);
  gemm_proj3<<<dim3(256, 3), 256, 0, stream>>>(Q, K, WT, bq, bk, bv, mask, qbuf, kbuf, vtmp);
  vtrans_kernel<<<dim3(8, 16, 8), 256, 0, stream>>>(vtmp, vTb);
  for (int h0 = 0; h0 < 8; h0 += nh) {
    attn_score<<<nh * 512, 512, 0, stream>>>(qbuf, kbuf, U, mbits, P, h0, lnh);
    attn_pv<<<nh * 64, 512, 0, stream>>>(P, vTb, qbuf, mask, O32, h0, lnh);
  }
  gemm_final<<<256, 256, 0, stream>>>(O32, WT + 3 * 262144, bo, mask, O32, out);
}

// Round 9
// 280.001 us; speedup vs baseline: 1.1071x; 1.1071x over previous
//
#include <hip/hip_runtime.h>

#define B_   8
#define N_   1024
#define D_   512
#define H_   8
#define DH_  64
#define SCALE_ 0.044194173824159216f   // 1/sqrt(512)
#define LOG2E_ 1.4426950408889634f

typedef __attribute__((ext_vector_type(8))) short bf16x8;
typedef __attribute__((ext_vector_type(4))) float f32x4;
typedef __attribute__((ext_vector_type(8))) unsigned short us8;
typedef __attribute__((ext_vector_type(4))) unsigned int u32x4;

__device__ __forceinline__ unsigned short f2bf(float f) {
  unsigned u = __builtin_bit_cast(unsigned, f);
  u += 0x7fffu + ((u >> 16) & 1u);           // RNE
  return (unsigned short)(u >> 16);
}
__device__ __forceinline__ float bf2f(unsigned short h) {
  unsigned u = ((unsigned)h) << 16;
  return __builtin_bit_cast(float, u);
}
__device__ __forceinline__ void gl_lds16(const void* g, void* l) {
  __builtin_amdgcn_global_load_lds(
      (const __attribute__((address_space(1))) unsigned int*)g,
      (__attribute__((address_space(3))) unsigned int*)l, 16, 0, 0);
}
__device__ __forceinline__ unsigned cvt_pk_bf16(float lo, float hi) {
  unsigned r;
  asm("v_cvt_pk_bf16_f32 %0, %1, %2" : "=v"(r) : "v"(lo), "v"(hi));
  return r;
}
#define MFMA16(a, b, c) __builtin_amdgcn_mfma_f32_16x16x32_bf16((a), (b), (c), 0, 0, 0)

// ---------------------------------------------------------------------------
// prep: WT_swz[mat][n][kmap] = bf16(W[k][n]); kmap XOR-swizzled so that a
// LINEAR global_load_lds copy + XOR on the ds_read side is bank-conflict-free.
// ---------------------------------------------------------------------------
__global__ void prep_w(const float* __restrict__ Wq, const float* __restrict__ Wk,
                       const float* __restrict__ Wv, const float* __restrict__ Wo,
                       unsigned short* __restrict__ WT) {
  int idx = blockIdx.x * 256 + threadIdx.x;          // 4 * 512 * 512 total
  int mat = idx >> 18;
  int rem = idx & 0x3FFFF;
  int k = rem >> 9, n = rem & 511;
  const float* W = (mat == 0) ? Wq : (mat == 1) ? Wk : (mat == 2) ? Wv : Wo;
  float v = W[(size_t)k * 512 + n];
  int kmap = (k & ~63) | ((k & 63) ^ ((n & 7) << 3));
  WT[(size_t)mat * 262144 + (size_t)n * 512 + kmap] = f2bf(v);
}

// mbits[j] bit b = (mask[b][j] != 0)
__global__ void prep_mask(const float* __restrict__ mask, unsigned* __restrict__ mbits) {
  int j = blockIdx.x * 256 + threadIdx.x;            // 1024 total
  unsigned r = 0;
#pragma unroll
  for (int bb = 0; bb < 8; ++bb) r |= (mask[bb * N_ + j] != 0.f ? 1u : 0u) << bb;
  mbits[j] = r;
}

// ---------------------------------------------------------------------------
// GEMM core body (128x128 tile, BK=64, 4 waves 2x2, wave = 64x64 out)
// ---------------------------------------------------------------------------
#define GEMM_BODY(A, W, bias, EPILOGUE)                                          \
  __shared__ unsigned short Alds[2][128][72];                                    \
  __shared__ unsigned short Blds[2][128 * 64];                                   \
  const int t = threadIdx.x, w = t >> 6, l = t & 63;                             \
  const int wr = w >> 1, wc = w & 1;                                             \
  const int lm = l & 15, lg = l >> 4;                                            \
  const int bm = blockIdx.x >> 2, bn = blockIdx.x & 3;                           \
  f32x4 acc[4][4];                                                               \
  _Pragma("unroll") for (int mt = 0; mt < 4; ++mt)                               \
  _Pragma("unroll") for (int nt = 0; nt < 4; ++nt)                               \
      acc[mt][nt] = f32x4{0.f, 0.f, 0.f, 0.f};                                   \
  float4 areg[8];                                                                \
  auto loadA = [&](int kt) {                                                     \
    _Pragma("unroll") for (int p = 0; p < 8; ++p) {                              \
      int row = (t >> 4) + p * 16, col = (t & 15) * 4;                           \
      areg[p] = *(const float4*)&A[((size_t)(bm * 128 + row)) * 512 + kt * 64 + col]; \
    }                                                                            \
  };                                                                             \
  auto issueB = [&](int kt, int sb) {                                            \
    _Pragma("unroll") for (int p = 0; p < 4; ++p) {                              \
      int chunk = w * 4 + p;                                                     \
      int row = chunk * 8 + (l >> 3), gc = kt * 64 + (l & 7) * 8;                \
      gl_lds16(&W[((size_t)(bn * 128 + row)) * 512 + gc],                        \
               &Blds[sb][chunk * 512 + l * 8]);                                  \
    }                                                                            \
  };                                                                             \
  auto writeA = [&](int sb) {                                                    \
    _Pragma("unroll") for (int p = 0; p < 8; ++p) {                              \
      int row = (t >> 4) + p * 16, col = (t & 15) * 4;                           \
      float4 v = areg[p];                                                        \
      uint2 d;                                                                   \
      d.x = (unsigned)f2bf(v.x) | ((unsigned)f2bf(v.y) << 16);                   \
      d.y = (unsigned)f2bf(v.z) | ((unsigned)f2bf(v.w) << 16);                   \
      *(uint2*)&Alds[sb][row][col] = d;                                          \
    }                                                                            \
  };                                                                             \
  loadA(0); issueB(0, 0); writeA(0);                                             \
  __syncthreads();                                                               \
  int buf = 0;                                                                   \
  for (int kt = 0; kt < 8; ++kt) {                                               \
    if (kt + 1 < 8) { loadA(kt + 1); issueB(kt + 1, buf ^ 1); }                  \
    _Pragma("unroll") for (int kk = 0; kk < 2; ++kk) {                           \
      bf16x8 af[4], bfv[4];                                                      \
      _Pragma("unroll") for (int mt = 0; mt < 4; ++mt)                           \
        af[mt] = *(const bf16x8*)&Alds[buf][wr * 64 + mt * 16 + lm][kk * 32 + lg * 8]; \
      _Pragma("unroll") for (int nt = 0; nt < 4; ++nt) {                         \
        int rr = wc * 64 + nt * 16 + lm;                                         \
        int c = (kk * 32 + lg * 8) ^ ((rr & 7) << 3);                            \
        bfv[nt] = *(const bf16x8*)&Blds[buf][rr * 64 + c];                       \
      }                                                                          \
      _Pragma("unroll") for (int mt = 0; mt < 4; ++mt)                           \
      _Pragma("unroll") for (int nt = 0; nt < 4; ++nt)                           \
          acc[mt][nt] = MFMA16(af[mt], bfv[nt], acc[mt][nt]);                    \
    }                                                                            \
    if (kt + 1 < 8) writeA(buf ^ 1);                                             \
    __syncthreads();                                                             \
    buf ^= 1;                                                                    \
  }                                                                              \
  _Pragma("unroll") for (int mt = 0; mt < 4; ++mt)                               \
  _Pragma("unroll") for (int nt = 0; nt < 4; ++nt) {                             \
    int gn = bn * 128 + wc * 64 + nt * 16 + lm;                                  \
    float bv_ = bias[gn];                                                        \
    _Pragma("unroll") for (int e = 0; e < 4; ++e) {                              \
      int gm = bm * 128 + wr * 64 + mt * 16 + lg * 4 + e;                        \
      float v = acc[mt][nt][e] + bv_;                                            \
      size_t off = (size_t)gm * 512 + gn;                                        \
      EPILOGUE                                                                   \
    }                                                                            \
  }

// fused 3 projection GEMMs: blockIdx.y = {0:Q->qb, 1:K->kb, 2:K->vtmp}
__global__ __launch_bounds__(256, 2) void gemm_proj3(
    const float* __restrict__ Q, const float* __restrict__ K,
    const unsigned short* __restrict__ WT,
    const float* __restrict__ bq, const float* __restrict__ bk,
    const float* __restrict__ bv, const float* __restrict__ mask,
    unsigned short* __restrict__ qb, unsigned short* __restrict__ kb,
    unsigned short* __restrict__ vtmp) {
  const int mat = blockIdx.y;
  const float* A = (mat == 0) ? Q : K;
  const unsigned short* W = WT + (size_t)mat * 262144;
  const float* bias = (mat == 0) ? bq : (mat == 1) ? bk : bv;
  unsigned short* outp = (mat == 0) ? qb : (mat == 1) ? kb : vtmp;
  GEMM_BODY(A, W, bias, { outp[off] = f2bf(v * mask[gm]); })
}

// final GEMM: out_f32 = resid + relu(acc + bias) * mask
__global__ __launch_bounds__(256, 2) void gemm_final(
    const float* __restrict__ A, const unsigned short* __restrict__ W,
    const float* __restrict__ bias, const float* __restrict__ mask,
    const float* __restrict__ resid, float* __restrict__ outp) {
  GEMM_BODY(A, W, bias, { outp[off] = resid[off] + fmaxf(v, 0.f) * mask[gm]; })
}

// ---------------------------------------------------------------------------
// v transpose: vtmp[b][n][d] (bf16) -> vT[b][d][n] (bf16)
// ---------------------------------------------------------------------------
__global__ void vtrans_kernel(const unsigned short* __restrict__ vtmp,
                              unsigned short* __restrict__ vT) {
  __shared__ unsigned short T[64][72];
  int b = blockIdx.x, ntile = blockIdx.y, dtile = blockIdx.z;
  int n0 = ntile * 64, d0 = dtile * 64;
  int t = threadIdx.x;
#pragma unroll
  for (int p = 0; p < 2; ++p) {
    int r = (t >> 3) + p * 32;
    int c = (t & 7) * 8;
    *(us8*)&T[r][c] = *(const us8*)&vtmp[((size_t)(b * N_ + n0 + r)) * D_ + d0 + c];
  }
  __syncthreads();
#pragma unroll
  for (int p = 0; p < 2; ++p) {
    int r = (t >> 3) + p * 32;   // d-local
    int c = (t & 7) * 8;         // n-local
    us8 v;
#pragma unroll
    for (int e = 0; e < 8; ++e) v[e] = T[c + e][r];
    *(us8*)&vT[((size_t)(b * D_ + d0 + r)) * N_ + n0 + c] = v;
  }
}

// ---------------------------------------------------------------------------
// attn_score v2: block = (h, 32i x 32j). 8 waves = 8 batches.
//  phase1: QK^T (8 MFMA/wave) -> Slds[b][i][j+pad36]; U tile staged to LDS
//          via global_load_lds in NATIVE [i][j][b] order (16B/lane contiguous
//          = ideal transaction pattern; r8 failure was 64-line strided loads).
//  barrier. phase2: thread(i,j): p[b] = mask_j ? exp(S*scale + U) : 0,
//          written back into Slds in place (conflict-free).
//  barrier. phase3: 256 threads (b,i) pack row to bf16, store P as BLOCKED
//          16KB tiles [tile][b][32][32] -> fat contiguous stores, and pv
//          reads become contiguous 1KB/wave-instr.
// ---------------------------------------------------------------------------
__global__ __launch_bounds__(512, 2) void attn_score(
    const unsigned short* __restrict__ qb, const unsigned short* __restrict__ kb,
    const float* __restrict__ U, const unsigned* __restrict__ mbits,
    unsigned short* __restrict__ P, int h0, int lnh) {
  __shared__ float Ulds[8192];        // [i32][j32][b8] native, 32 KB
  __shared__ float Slds[8 * 1152];    // [b][i32][36]   36 KB
  const int t = threadIdx.x, w = t >> 6, l = t & 63;
  const int bid = (int)blockIdx.x;
  const int hh = bid & ((1 << lnh) - 1);
  const int h = h0 + hh;
  const int r = bid >> lnh;
  const int it = r >> 5, jt = r & 31;
  const int i0 = it * 32, j0 = jt * 32;
  const int lm = l & 15, lg = l >> 4;

  // ---- U staging: 4 rounds x (8 waves x 1KB contiguous) = 32 KB
  {
    const float* Ub = U + (((size_t)h * N_ + i0) * N_ + j0) * B_;
#pragma unroll
    for (int rr = 0; rr < 4; ++rr) {
      int i = rr * 8 + w;
      gl_lds16(Ub + (size_t)i * (N_ * B_) + l * 4, &Ulds[rr * 2048 + w * 256 + l * 4]);
    }
  }
  const unsigned mbw = mbits[j0 + (t & 31)];

  // ---- phase 1: per-wave QK^T for batch b = w
  {
    const unsigned short* qbase = qb + ((size_t)w * N_ + i0 + lm) * D_ + h * DH_ + lg * 8;
    const unsigned short* kbase = kb + ((size_t)w * N_ + j0 + lm) * D_ + h * DH_ + lg * 8;
    bf16x8 qf[2][2], kf[2][2];
#pragma unroll
    for (int mt = 0; mt < 2; ++mt)
#pragma unroll
      for (int kt = 0; kt < 2; ++kt) {
        qf[mt][kt] = *(const bf16x8*)(qbase + (size_t)(mt * 16) * D_ + kt * 32);
        kf[mt][kt] = *(const bf16x8*)(kbase + (size_t)(mt * 16) * D_ + kt * 32);
      }
    f32x4 acc[2][2];
#pragma unroll
    for (int mt = 0; mt < 2; ++mt)
#pragma unroll
      for (int nt = 0; nt < 2; ++nt) acc[mt][nt] = f32x4{0.f, 0.f, 0.f, 0.f};
#pragma unroll
    for (int kt = 0; kt < 2; ++kt)
#pragma unroll
      for (int mt = 0; mt < 2; ++mt)
#pragma unroll
        for (int nt = 0; nt < 2; ++nt)
          acc[mt][nt] = MFMA16(qf[mt][kt], kf[nt][kt], acc[mt][nt]);
    // S -> Slds[b][i][j]  (pad 36: ~2-way writes)
#pragma unroll
    for (int mt = 0; mt < 2; ++mt)
#pragma unroll
      for (int nt = 0; nt < 2; ++nt)
#pragma unroll
        for (int e = 0; e < 4; ++e)
          Slds[w * 1152 + (mt * 16 + lg * 4 + e) * 36 + nt * 16 + lm] = acc[mt][nt][e];
  }
  __syncthreads();

  // ---- phase 2: thread (i,j) -> p[b] = exp(S*scale + U), in-place
  {
    const int pj = t & 31, pi0 = t >> 5;   // pi0 in [0,16)
#pragma unroll
    for (int ii = 0; ii < 2; ++ii) {
      const int i = pi0 + ii * 16;
      f32x4 u0 = *(const f32x4*)&Ulds[(i * 32 + pj) * 8];
      f32x4 u1 = *(const f32x4*)&Ulds[(i * 32 + pj) * 8 + 4];
      float uu[8] = {u0[0], u0[1], u0[2], u0[3], u1[0], u1[1], u1[2], u1[3]};
#pragma unroll
      for (int b = 0; b < 8; ++b) {
        const int sa = b * 1152 + i * 36 + pj;
        float s = Slds[sa] * SCALE_ + uu[b];
        Slds[sa] = ((mbw >> b) & 1) ? exp2f(s * LOG2E_) : 0.f;
      }
    }
  }
  __syncthreads();

  // ---- phase 3: pack P rows -> blocked global tile [tile][b][32][32] bf16
  if (t < 256) {
    const int b3 = t >> 5, i3 = t & 31;
    const float* row = &Slds[b3 * 1152 + i3 * 36];
    u32x4 o[2];
#pragma unroll
    for (int q = 0; q < 4; ++q) {
      f32x4 p4 = *(const f32x4*)(row + q * 8);
      f32x4 p5 = *(const f32x4*)(row + q * 8 + 4);
      o[q >> 1][(q & 1) * 2]     = cvt_pk_bf16(p4[0], p4[1]);
      o[q >> 1][(q & 1) * 2 + 1] = cvt_pk_bf16(p4[2], p4[3]);
      // second half packed below
      (void)p5;
    }
    // repack cleanly: 32 floats -> 16 u32
    unsigned pk[16];
#pragma unroll
    for (int q = 0; q < 16; ++q) {
      float a = row[q * 2], bqv = row[q * 2 + 1];
      pk[q] = cvt_pk_bf16(a, bqv);
    }
    unsigned short* Pt = P + ((size_t)((hh * 32 + it) * 32 + jt)) * 8192 + (b3 * 32 + i3) * 32;
#pragma unroll
    for (int c = 0; c < 4; ++c)
      *(u32x4*)(Pt + c * 8) = u32x4{pk[c * 4], pk[c * 4 + 1], pk[c * 4 + 2], pk[c * 4 + 3]};
  }
}

// ---------------------------------------------------------------------------
// attn_pv v2: O = mask_i * (q + P@V / rowsum(P)).  256 thr, 4 waves, no LDS.
// Block = (h, b, it16): wave w -> 16 rows (it*64 + w*16). P read from blocked
// tiles: each wave instr = 16 rows x 64B = contiguous 1KB (ideal pattern).
// Denominator = extra MFMA vs ones-column (same D-layout as acc -> no shfl).
// ---------------------------------------------------------------------------
__global__ __launch_bounds__(256, 4) void attn_pv(
    const unsigned short* __restrict__ P, const unsigned short* __restrict__ vT,
    const unsigned short* __restrict__ qb, const float* __restrict__ mask,
    float* __restrict__ O32, int h0, int lnh) {
  const int t = threadIdx.x, w = t >> 6, l = t & 63;
  const int bid = (int)blockIdx.x;
  const int hh = bid & ((1 << lnh) - 1);
  const int h = h0 + hh;
  const int r = bid >> lnh;
  const int b = r & 7, it = r >> 3;
  const int lm = l & 15, lg = l >> 4;
  const int i0row = it * 64 + w * 16;
  const int it2 = it * 2 + (w >> 1);        // score-tile row index
  const int rowin = (w & 1) * 16 + lm;      // row within score tile

  const unsigned short* Pt = P + ((size_t)(hh * 32 + it2)) * 32 * 8192 +
                             (b * 32 + rowin) * 32 + lg * 8;
  const unsigned short* Vb = vT + ((size_t)b * D_ + h * DH_ + lm) * N_ + lg * 8;

  bf16x8 ones;
#pragma unroll
  for (int e = 0; e < 8; ++e) ones[e] = (short)0x3F80;

  f32x4 acc[4];
#pragma unroll
  for (int nt = 0; nt < 4; ++nt) acc[nt] = f32x4{0.f, 0.f, 0.f, 0.f};
  f32x4 dsum = f32x4{0.f, 0.f, 0.f, 0.f};

#pragma unroll 4
  for (int ks = 0; ks < 32; ++ks) {
    bf16x8 pf = *(const bf16x8*)(Pt + (size_t)ks * 8192);
#pragma unroll
    for (int nt = 0; nt < 4; ++nt) {
      bf16x8 vf = *(const bf16x8*)(Vb + (size_t)(nt * 16) * N_ + ks * 32);
      acc[nt] = MFMA16(pf, vf, acc[nt]);
    }
    dsum = MFMA16(pf, ones, dsum);
  }

#pragma unroll
  for (int e = 0; e < 4; ++e) {
    int gi = i0row + lg * 4 + e;
    float mi = mask[b * N_ + gi];
    float rD = 1.f / (dsum[e] + 1e-16f);
#pragma unroll
    for (int nt = 0; nt < 4; ++nt) {
      size_t off = ((size_t)b * N_ + gi) * D_ + h * DH_ + lm + nt * 16;
      O32[off] = mi * (bf2f(qb[off]) + acc[nt][e] * rD);
    }
  }
}

// ---------------------------------------------------------------------------
extern "C" void kernel_launch(void* const* d_in, const int* in_sizes, int n_in,
                              void* d_out, int out_size, void* d_ws, size_t ws_size,
                              hipStream_t stream) {
  const float* Q    = (const float*)d_in[0];
  const float* K    = (const float*)d_in[1];
  const float* U    = (const float*)d_in[2];
  const float* mask = (const float*)d_in[3];
  const float* Wq   = (const float*)d_in[4];
  const float* bq   = (const float*)d_in[5];
  const float* Wk   = (const float*)d_in[6];
  const float* bk   = (const float*)d_in[7];
  const float* Wv   = (const float*)d_in[8];
  const float* bv   = (const float*)d_in[9];
  const float* Wo   = (const float*)d_in[10];
  const float* bo   = (const float*)d_in[11];
  float* out = (float*)d_out;

  char* ws = (char*)d_ws;
  const size_t MB = 1ull << 20;
  unsigned short* WT   = (unsigned short*)(ws);            // [0, 2) MB
  unsigned short* qbuf = (unsigned short*)(ws + 2 * MB);   // [2, 10)
  unsigned short* kbuf = (unsigned short*)(ws + 10 * MB);  // [10, 18)
  unsigned short* vTb  = (unsigned short*)(ws + 18 * MB);  // [18, 26)
  float*          O32  = (float*)(ws + 26 * MB);           // [26, 42)
  unsigned*       mbits= (unsigned*)(ws + 42 * MB);        // [42, 42.004)
  unsigned short* vtmp = (unsigned short*)(ws + 43 * MB);  // [43, 51) overlay in P region
  unsigned short* P    = (unsigned short*)(ws + 43 * MB);  // [43, 43 + nh*16)

  // choose h-group size from available workspace (P = nh * 16 MB)
  int lnh;
  if      (ws_size >= (43 + 128) * MB) lnh = 3;
  else if (ws_size >= (43 + 64) * MB)  lnh = 2;
  else if (ws_size >= (43 + 32) * MB)  lnh = 1;
  else                                 lnh = 0;
  const int nh = 1 << lnh;

  prep_w<<<4096, 256, 0, stream>>>(Wq, Wk, Wv, Wo, WT);
  prep_mask<<<4, 256, 0, stream>>>(mask, mbits);
  gemm_proj3<<<dim3(256, 3), 256, 0, stream>>>(Q, K, WT, bq, bk, bv, mask, qbuf, kbuf, vtmp);
  vtrans_kernel<<<dim3(8, 16, 8), 256, 0, stream>>>(vtmp, vTb);
  for (int h0 = 0; h0 < 8; h0 += nh) {
    attn_score<<<nh * 1024, 512, 0, stream>>>(qbuf, kbuf, U, mbits, P, h0, lnh);
    attn_pv<<<nh * 128, 256, 0, stream>>>(P, vTb, qbuf, mask, O32, h0, lnh);
  }
  gemm_final<<<256, 256, 0, stream>>>(O32, WT + 3 * 262144, bo, mask, O32, out);
}